// Round 8
// baseline (76.826 us; speedup 1.0000x reference)
//
#include <hip/hip_runtime.h>
#include <math.h>

// out[b,o] = min_i(W[o,i]+X[b,i]) + max_i(W[o,i]+X[b,i])
// B=1024, OUT=1024, IN=512, fp32.
//
// R8: LDS-free main loop (R4-R7 were LDS-pipe-bound at ~19us floor; VALU
// floor is 13.6us). lane=b; each wave: 64 b x 8 o x full K. W via uniform
// broadcast dwordx4 (1 line/load), X via packed layout Xp[c][b][4] built by
// a small transpose kernel into d_ws -> coalesced dwordx4. No LDS, no
// barriers, no merge in main kernel. 2048 waves = 8/CU.

typedef float f4 __attribute__((ext_vector_type(4)));

constexpr int B_DIM  = 1024;
constexpr int O_DIM  = 1024;
constexpr int IN_DIM = 512;
constexpr int NCH    = IN_DIM / 4;   // 128 chunks of 4 k

// ---- pack kernel: Xp[c][b][4] = X[b][4c+j] ----
// 64x64 tile per block; transpose in LDS with odd-stride pad (69) ->
// conflict-free scalar writes and reads.
__global__ __launch_bounds__(256) void pack_x(const float* __restrict__ X,
                                              float* __restrict__ Xp) {
    __shared__ float t[64][69];        // t[i_local][b_local]
    const int b0 = blockIdx.x * 64;
    const int i0 = blockIdx.y * 64;
    const int l  = threadIdx.x & 63;
    const int q  = threadIdx.x >> 6;   // 0..3
#pragma unroll
    for (int r = 0; r < 16; ++r) {
        const int bl = q * 16 + r;
        t[l][bl] = X[(size_t)(b0 + bl) * IN_DIM + i0 + l];  // coalesced read
    }
    __syncthreads();
#pragma unroll
    for (int jj = 0; jj < 4; ++jj) {
        const int cl = q * 4 + jj;           // local chunk 0..15
        const int cg = (i0 >> 2) + cl;       // global chunk
        f4 v;
        v[0] = t[cl * 4 + 0][l];
        v[1] = t[cl * 4 + 1][l];
        v[2] = t[cl * 4 + 2][l];
        v[3] = t[cl * 4 + 3][l];
        *(f4*)(Xp + ((size_t)cg * 1024 + b0 + l) * 4) = v;  // coalesced write
    }
}

// ---- main kernel ----
// PACKED=1: Xs = Xp[c][b][4] (chunk stride 4096 floats, coalesced)
// PACKED=0: Xs = X[b][i]     (chunk stride 4 floats, per-lane row scatter)
template <int PACKED>
__global__ __launch_bounds__(256) void tropical_main(
    const float* __restrict__ Xs, const float* __restrict__ W,
    float* __restrict__ out) {
    const int tid  = threadIdx.x;
    const int wv   = tid >> 6;
    const int lane = tid & 63;
    const int b0   = blockIdx.y * 64;
    const int o0   = (blockIdx.x * 4 + wv) * 8;

    const float* xbase = PACKED ? Xs + ((size_t)b0 + lane) * 4
                                : Xs + (size_t)(b0 + lane) * IN_DIM;
    const size_t xstep = PACKED ? 4096 : 4;   // floats per chunk
    const float* wp = W + (size_t)o0 * IN_DIM;

    float mn[8], mx[8];
#pragma unroll
    for (int o = 0; o < 8; ++o) { mn[o] = INFINITY; mx[o] = -INFINITY; }

    f4 xA, xB;
    f4 wA[8], wB[8];

#define LX(R, c) (R) = *(const f4*)(xbase + (size_t)(c) * xstep)
#define LW(S, c)                                                              \
    do {                                                                      \
        _Pragma("unroll")                                                     \
        for (int o_ = 0; o_ < 8; ++o_)                                        \
            S[o_] = *(const f4*)(wp + o_ * IN_DIM + (c) * 4);                 \
    } while (0)
#define CMP(XR, WS)                                                           \
    do {                                                                      \
        _Pragma("unroll")                                                     \
        for (int o_ = 0; o_ < 8; ++o_) {                                      \
            float s0_ = XR[0] + WS[o_][0];                                    \
            float s1_ = XR[1] + WS[o_][1];                                    \
            asm("v_min3_f32 %0, %1, %2, %0"                                   \
                : "+v"(mn[o_]) : "v"(s0_), "v"(s1_));                         \
            asm("v_max3_f32 %0, %1, %2, %0"                                   \
                : "+v"(mx[o_]) : "v"(s0_), "v"(s1_));                         \
            float s2_ = XR[2] + WS[o_][2];                                    \
            float s3_ = XR[3] + WS[o_][3];                                    \
            asm("v_min3_f32 %0, %1, %2, %0"                                   \
                : "+v"(mn[o_]) : "v"(s2_), "v"(s3_));                         \
            asm("v_max3_f32 %0, %1, %2, %0"                                   \
                : "+v"(mx[o_]) : "v"(s2_), "v"(s3_));                         \
        }                                                                     \
    } while (0)

    LX(xA, 0);
    LW(wA, 0);
#pragma unroll 1
    for (int c = 0; c < NCH; c += 2) {
        LX(xB, c + 1);              // prefetch odd chunk
        LW(wB, c + 1);
        CMP(xA, wA);
        const int c2 = (c + 2) & (NCH - 1);   // last iter wraps (harmless)
        LX(xA, c2);                 // prefetch next even chunk
        LW(wA, c2);
        CMP(xB, wB);
    }
#undef LX
#undef LW
#undef CMP

    float* op = out + (size_t)(b0 + lane) * O_DIM + o0;
    f4 r0, r1;
#pragma unroll
    for (int o = 0; o < 4; ++o) r0[o] = mn[o] + mx[o];
#pragma unroll
    for (int o = 0; o < 4; ++o) r1[o] = mn[4 + o] + mx[4 + o];
    *(f4*)(op)     = r0;
    *(f4*)(op + 4) = r1;
}

extern "C" void kernel_launch(void* const* d_in, const int* in_sizes, int n_in,
                              void* d_out, int out_size, void* d_ws, size_t ws_size,
                              hipStream_t stream) {
    (void)in_sizes; (void)n_in; (void)out_size;
    const float* X = (const float*)d_in[0];
    const float* W = (const float*)d_in[1];
    float* out     = (float*)d_out;

    const size_t need = (size_t)IN_DIM * B_DIM * sizeof(float);  // 2 MB
    dim3 mgrid(O_DIM / 32, B_DIM / 64);   // (32, 16) = 512 blocks, 4 waves each

    if (ws_size >= need) {
        float* Xp = (float*)d_ws;
        pack_x<<<dim3(B_DIM / 64, IN_DIM / 64), dim3(256), 0, stream>>>(X, Xp);
        tropical_main<1><<<mgrid, dim3(256), 0, stream>>>(Xp, W, out);
    } else {
        tropical_main<0><<<mgrid, dim3(256), 0, stream>>>(X, W, out);
    }
}

// Round 9
// 37.057 us; speedup vs baseline: 2.0732x; 2.0732x over previous
//
#include <hip/hip_runtime.h>
#include <math.h>

// out[b,o] = min_i(W[o,i]+X[b,i]) + max_i(W[o,i]+X[b,i])
// B=1024, OUT=1024, IN=512, fp32.
//
// R9: minimize register-fill bytes (the real pipe currency).
// 64x64 tile, 512-thread block (8 waves), split-K x8 (KW=64), grid 256 =
// 1 block/CU = 2 waves/SIMD. 8x8 per-lane micro -> 1 B/triple into VGPRs
// (2 MB/CU via LDS ~10us) vs R6's 1.5 B (3 MB). k-PAIRED LDS layout so
// (k,k+1) sit in one register pair -> f2 adds (v_pk_add candidates) feeding
// asm v_min3/v_max3. XOR bank-spread keeps reads conflict-free.
// amdgpu_waves_per_eu(2,2) pins the 256-VGPR budget (launch_bounds' 2nd arg
// is CUDA blocks-per-SM semantics -> caused the R2/R3 128-VGPR spills).
// Wave-private dbuf LDS, zero main-loop barriers, 3-round phased merge tree.

typedef float f4 __attribute__((ext_vector_type(4)));
typedef float f2 __attribute__((ext_vector_type(2)));

constexpr int B_DIM  = 1024;
constexpr int O_DIM  = 1024;
constexpr int IN_DIM = 512;

constexpr int TILE   = 64;
constexpr int KW     = 64;          // k per wave (512 / 8 waves)
constexpr int BK     = 8;           // k per staged chunk (= 4 k-pairs)
constexpr int NSTAGE = KW / BK;     // 8

// LDS row layout (one kp-row = 64 a-pairs = 512 B):
//   byte offset of pair-block a: poff(a) = a*8 ^ (((a>>4)&3)<<4)
// bijective (XOR of bits 4-5 with bits 7-8); read quads land on distinct
// bank-groups {0,16,4,20,8,24,12,28} -> conflict-free b128 reads.

__global__ __attribute__((amdgpu_flat_work_group_size(512, 512)))
           __attribute__((amdgpu_waves_per_eu(2, 2)))
void tropical_gemm(const float* __restrict__ X, const float* __restrict__ Wm,
                   float* __restrict__ out) {
    __shared__ float lds[16384];   // 64 KB: 8 waves x 8 KB; merge overlay 4x16KB

    const int tid  = threadIdx.x;
    const int w    = tid >> 6;      // wave 0..7
    const int lane = tid & 63;
    const int im   = lane >> 3;     // micro-row block 0..7 (X rows a=im*8..+7)
    const int in_  = lane & 7;      // micro-col block 0..7 (W cols b=in_*8..+7)
    const int b0   = blockIdx.y * TILE;
    const int o0   = blockIdx.x * TILE;

    const int xs = (im >> 1) & 3;   // read-quad XOR for X
    const int ws = (in_ >> 1) & 3;  // read-quad XOR for W
    const int wo = (lane * 8) ^ (((lane >> 4) & 3) << 4);  // staging write off

    const float* Xp = X  + (size_t)(b0 + lane) * IN_DIM + w * KW;
    const float* Wp = Wm + (size_t)(o0 + lane) * IN_DIM + w * KW;

    char* wbase = (char*)lds + w * 8192;  // [buf 4KB][X 2KB | W 2KB]

    float mn[8][8], mx[8][8];
#pragma unroll
    for (int i = 0; i < 8; ++i)
#pragma unroll
        for (int j = 0; j < 8; ++j) { mn[i][j] = INFINITY; mx[i][j] = -INFINITY; }

    // stage one 8k chunk as 4 kp-rows: pairs (k,k+1) at poff(row)
#define STAGE(bufsel)                                                         \
    do {                                                                      \
        char* d_ = wbase + (bufsel) * 4096;                                   \
        *(f2*)(d_ + 0 * 512 + wo)        = __builtin_shufflevector(xa, xa, 0, 1); \
        *(f2*)(d_ + 1 * 512 + wo)        = __builtin_shufflevector(xa, xa, 2, 3); \
        *(f2*)(d_ + 2 * 512 + wo)        = __builtin_shufflevector(xb, xb, 0, 1); \
        *(f2*)(d_ + 3 * 512 + wo)        = __builtin_shufflevector(xb, xb, 2, 3); \
        *(f2*)(d_ + 2048 + 0 * 512 + wo) = __builtin_shufflevector(wa, wa, 0, 1); \
        *(f2*)(d_ + 2048 + 1 * 512 + wo) = __builtin_shufflevector(wa, wa, 2, 3); \
        *(f2*)(d_ + 2048 + 2 * 512 + wo) = __builtin_shufflevector(wb, wb, 0, 1); \
        *(f2*)(d_ + 2048 + 3 * 512 + wo) = __builtin_shufflevector(wb, wb, 2, 3); \
    } while (0)

    // load one kp's fragments: 4 X b128 (8 a-pairs) + 4 W b128 (8 b-pairs)
#define LOADQ(P, kp)                                                          \
    do {                                                                      \
        P##x0 = *(const f4*)(sX + (kp) * 512 + im * 64 + ((0 ^ xs) << 4));    \
        P##x1 = *(const f4*)(sX + (kp) * 512 + im * 64 + ((1 ^ xs) << 4));    \
        P##x2 = *(const f4*)(sX + (kp) * 512 + im * 64 + ((2 ^ xs) << 4));    \
        P##x3 = *(const f4*)(sX + (kp) * 512 + im * 64 + ((3 ^ xs) << 4));    \
        P##w0 = *(const f4*)(sW + (kp) * 512 + in_ * 64 + ((0 ^ ws) << 4));   \
        P##w1 = *(const f4*)(sW + (kp) * 512 + in_ * 64 + ((1 ^ ws) << 4));   \
        P##w2 = *(const f4*)(sW + (kp) * 512 + in_ * 64 + ((2 ^ ws) << 4));   \
        P##w3 = *(const f4*)(sW + (kp) * 512 + in_ * 64 + ((3 ^ ws) << 4));   \
    } while (0)

    // one x-pair (2 k's of row A) vs one w-quad (b-pairs 2BQ, 2BQ+1)
#define CB(WQ, XP, A, BQ)                                                     \
    do {                                                                      \
        f2 wlo_ = __builtin_shufflevector(WQ, WQ, 0, 1);                      \
        f2 whi_ = __builtin_shufflevector(WQ, WQ, 2, 3);                      \
        f2 s0_ = (XP) + wlo_;   /* f2 add -> v_pk_add_f32 candidate */        \
        f2 s1_ = (XP) + whi_;                                                 \
        asm("v_min3_f32 %0, %1, %2, %0"                                       \
            : "+v"(mn[A][2 * (BQ)]) : "v"(s0_[0]), "v"(s0_[1]));              \
        asm("v_max3_f32 %0, %1, %2, %0"                                       \
            : "+v"(mx[A][2 * (BQ)]) : "v"(s0_[0]), "v"(s0_[1]));              \
        asm("v_min3_f32 %0, %1, %2, %0"                                       \
            : "+v"(mn[A][2 * (BQ) + 1]) : "v"(s1_[0]), "v"(s1_[1]));          \
        asm("v_max3_f32 %0, %1, %2, %0"                                       \
            : "+v"(mx[A][2 * (BQ) + 1]) : "v"(s1_[0]), "v"(s1_[1]));          \
    } while (0)

#define CROW(P, XP, A)                                                        \
    do { CB(P##w0, XP, A, 0); CB(P##w1, XP, A, 1);                            \
         CB(P##w2, XP, A, 2); CB(P##w3, XP, A, 3); } while (0)

#define CQUAD(P, XQ, A0)                                                      \
    do {                                                                      \
        f2 xlo_ = __builtin_shufflevector(P##XQ, P##XQ, 0, 1);                \
        f2 xhi_ = __builtin_shufflevector(P##XQ, P##XQ, 2, 3);                \
        CROW(P, xlo_, A0); CROW(P, xhi_, (A0) + 1);                           \
    } while (0)

#define COMPUTE(P)                                                            \
    do { CQUAD(P, x0, 0); CQUAD(P, x1, 2);                                    \
         CQUAD(P, x2, 4); CQUAD(P, x3, 6); } while (0)

    // ---- prologue ----
    f4 xa = *(const f4*)(Xp);
    f4 xb = *(const f4*)(Xp + 4);
    f4 wa = *(const f4*)(Wp);
    f4 wb = *(const f4*)(Wp + 4);
    STAGE(0);

#pragma unroll 1
    for (int s = 0; s < NSTAGE; ++s) {
        if (s + 1 < NSTAGE) {   // prefetch next chunk's globals
            xa = *(const f4*)(Xp + (s + 1) * BK);
            xb = *(const f4*)(Xp + (s + 1) * BK + 4);
            wa = *(const f4*)(Wp + (s + 1) * BK);
            wb = *(const f4*)(Wp + (s + 1) * BK + 4);
        }

        const char* sX = wbase + (s & 1) * 4096;
        const char* sW = sX + 2048;

        f4 Ax0, Ax1, Ax2, Ax3, Aw0, Aw1, Aw2, Aw3;
        f4 Bx0, Bx1, Bx2, Bx3, Bw0, Bw1, Bw2, Bw3;

        LOADQ(A, 0);
        LOADQ(B, 1);
        COMPUTE(A);          // kp0 (B=kp1 in flight)
        LOADQ(A, 2);
        COMPUTE(B);          // kp1 (A=kp2 in flight)
        LOADQ(B, 3);
        COMPUTE(A);          // kp2 (B=kp3 in flight)
        COMPUTE(B);          // kp3

        if (s + 1 < NSTAGE) STAGE((s + 1) & 1);
    }
#undef STAGE
#undef LOADQ
#undef CB
#undef CROW
#undef CQUAD
#undef COMPUTE

    // ---- merge 8 wave partials: 3 rounds, mn/mx phased (16 KB slots) ----
#define DUMPMN(slot)                                                          \
    do {                                                                      \
        float* p_ = lds + (slot) * 4096 + lane * 4;                           \
        _Pragma("unroll")                                                     \
        for (int r_ = 0; r_ < 8; ++r_) {                                      \
            f4 lo_ = {mn[r_][0], mn[r_][1], mn[r_][2], mn[r_][3]};            \
            f4 hi_ = {mn[r_][4], mn[r_][5], mn[r_][6], mn[r_][7]};            \
            *(f4*)(p_ + (2 * r_) * 256)     = lo_;                            \
            *(f4*)(p_ + (2 * r_ + 1) * 256) = hi_;                            \
        }                                                                     \
    } while (0)
#define DUMPMX(slot)                                                          \
    do {                                                                      \
        float* p_ = lds + (slot) * 4096 + lane * 4;                           \
        _Pragma("unroll")                                                     \
        for (int r_ = 0; r_ < 8; ++r_) {                                      \
            f4 lo_ = {mx[r_][0], mx[r_][1], mx[r_][2], mx[r_][3]};            \
            f4 hi_ = {mx[r_][4], mx[r_][5], mx[r_][6], mx[r_][7]};            \
            *(f4*)(p_ + (2 * r_) * 256)     = lo_;                            \
            *(f4*)(p_ + (2 * r_ + 1) * 256) = hi_;                            \
        }                                                                     \
    } while (0)
#define MERGEMN(slot)                                                         \
    do {                                                                      \
        const float* p_ = lds + (slot) * 4096 + lane * 4;                     \
        _Pragma("unroll")                                                     \
        for (int r_ = 0; r_ < 8; ++r_) {                                      \
            f4 lo_ = *(const f4*)(p_ + (2 * r_) * 256);                       \
            f4 hi_ = *(const f4*)(p_ + (2 * r_ + 1) * 256);                   \
            mn[r_][0] = fminf(mn[r_][0], lo_[0]);                             \
            mn[r_][1] = fminf(mn[r_][1], lo_[1]);                             \
            mn[r_][2] = fminf(mn[r_][2], lo_[2]);                             \
            mn[r_][3] = fminf(mn[r_][3], lo_[3]);                             \
            mn[r_][4] = fminf(mn[r_][4], hi_[0]);                             \
            mn[r_][5] = fminf(mn[r_][5], hi_[1]);                             \
            mn[r_][6] = fminf(mn[r_][6], hi_[2]);                             \
            mn[r_][7] = fminf(mn[r_][7], hi_[3]);                             \
        }                                                                     \
    } while (0)
#define MERGEMX(slot)                                                         \
    do {                                                                      \
        const float* p_ = lds + (slot) * 4096 + lane * 4;                     \
        _Pragma("unroll")                                                     \
        for (int r_ = 0; r_ < 8; ++r_) {                                      \
            f4 lo_ = *(const f4*)(p_ + (2 * r_) * 256);                       \
            f4 hi_ = *(const f4*)(p_ + (2 * r_ + 1) * 256);                   \
            mx[r_][0] = fmaxf(mx[r_][0], lo_[0]);                             \
            mx[r_][1] = fmaxf(mx[r_][1], lo_[1]);                             \
            mx[r_][2] = fmaxf(mx[r_][2], lo_[2]);                             \
            mx[r_][3] = fmaxf(mx[r_][3], lo_[3]);                             \
            mx[r_][4] = fmaxf(mx[r_][4], hi_[0]);                             \
            mx[r_][5] = fmaxf(mx[r_][5], hi_[1]);                             \
            mx[r_][6] = fmaxf(mx[r_][6], hi_[2]);                             \
            mx[r_][7] = fmaxf(mx[r_][7], hi_[3]);                             \
        }                                                                     \
    } while (0)

    __syncthreads();                       // main-loop LDS use complete
    // Round 1 (8->4), mn phase then mx phase
    if (w >= 4) DUMPMN(w - 4);
    __syncthreads();
    if (w < 4) MERGEMN(w);
    __syncthreads();
    if (w >= 4) DUMPMX(w - 4);
    __syncthreads();
    if (w < 4) MERGEMX(w);
    __syncthreads();
    // Round 2 (4->2): w2,w3 dump both arrays
    if (w == 2) { DUMPMN(0); DUMPMX(1); }
    if (w == 3) { DUMPMN(2); DUMPMX(3); }
    __syncthreads();
    if (w == 0) { MERGEMN(0); MERGEMX(1); }
    if (w == 1) { MERGEMN(2); MERGEMX(3); }
    __syncthreads();
    // Round 3 (2->1)
    if (w == 1) { DUMPMN(0); DUMPMX(1); }
    __syncthreads();
    if (w == 0) {
        MERGEMN(0); MERGEMX(1);
        float* op = out + (size_t)(b0 + im * 8) * O_DIM + o0 + in_ * 8;
#pragma unroll
        for (int r = 0; r < 8; ++r) {
            f4 v0 = {mn[r][0] + mx[r][0], mn[r][1] + mx[r][1],
                     mn[r][2] + mx[r][2], mn[r][3] + mx[r][3]};
            f4 v1 = {mn[r][4] + mx[r][4], mn[r][5] + mx[r][5],
                     mn[r][6] + mx[r][6], mn[r][7] + mx[r][7]};
            *(f4*)(op + (size_t)r * O_DIM)     = v0;
            *(f4*)(op + (size_t)r * O_DIM + 4) = v1;
        }
    }
#undef DUMPMN
#undef DUMPMX
#undef MERGEMN
#undef MERGEMX
}

extern "C" void kernel_launch(void* const* d_in, const int* in_sizes, int n_in,
                              void* d_out, int out_size, void* d_ws, size_t ws_size,
                              hipStream_t stream) {
    (void)in_sizes; (void)n_in; (void)d_ws; (void)ws_size; (void)out_size;
    const float* X = (const float*)d_in[0];
    const float* W = (const float*)d_in[1];
    float* out     = (float*)d_out;

    dim3 grid(O_DIM / TILE, B_DIM / TILE);  // (16,16) = 256 blocks = 1/CU
    tropical_gemm<<<grid, dim3(512), 0, stream>>>(X, W, out);
}